// Round 4
// baseline (388.988 us; speedup 1.0000x reference)
//
#include <hip/hip_runtime.h>
#include <cmath>
#include <cstdint>
#include <cstddef>

typedef unsigned long long u64;
typedef unsigned int u32;

#define NPX   2500
#define NANCH 22500
#define PRE_TOPK 10000
#define NWORDS 160      // 160*64 = 10240 bits per NMS row

struct AnchorBase { float b[36]; };

typedef __attribute__((ext_vector_type(8))) short bf16x8;
typedef __attribute__((ext_vector_type(4))) float f32x4;

__device__ inline unsigned short f2bf(float f) {
    u32 u = __float_as_uint(f);
    u32 r = u + 0x7fffu + ((u >> 16) & 1u);
    return (unsigned short)(r >> 16);
}
__device__ inline float bf2f(unsigned short h) {
    return __uint_as_float(((u32)h) << 16);
}

// ---------------------------------------------------------------------------
// KPREP: fused input prep (Xt bf16 hi/lo padded grid; W' bf16 hi/lo).
// ---------------------------------------------------------------------------
__global__ __launch_bounds__(256) void kprep(const float* __restrict__ feat,
                                             const float* __restrict__ wr,
                                             unsigned short* __restrict__ xthi,
                                             unsigned short* __restrict__ xtlo,
                                             unsigned short* __restrict__ whi,
                                             unsigned short* __restrict__ wlo)
{
    __shared__ float sh[4608];
    int bid = blockIdx.x;
    int t = threadIdx.x;
    if (bid < 416) {
        float (*tile)[65] = (float(*)[65])sh;
        int gr = bid >> 3;          // grid row 0..51
        int cc = bid & 7;           // c-chunk
        int tx = t & 63, ty = t >> 6;
        int y = gr - 1;
        bool rowok = (gr >= 1) && (gr <= 50);
#pragma unroll
        for (int i = 0; i < 16; ++i) {
            int c = i * 4 + ty;
            tile[c][tx] = (rowok && tx < 50)
                        ? feat[(size_t)(cc * 64 + c) * NPX + y * 50 + tx] : 0.f;
        }
        __syncthreads();
#pragma unroll
        for (int i = 0; i < 16; ++i) {
            int xp = i * 4 + ty;
            int cell = gr * 64 + xp;
            bool ok = rowok && xp >= 1 && xp <= 50;
            float v = ok ? tile[tx][xp - 1] : 0.f;
            unsigned short hi = f2bf(v);
            xthi[(size_t)cell * 512 + cc * 64 + tx] = hi;
            xtlo[(size_t)cell * 512 + cc * 64 + tx] = f2bf(v - bf2f(hi));
        }
    } else {
        int oc = bid - 416;         // 0..511
        for (int j = t; j < 4608; j += 256) sh[j] = wr[(size_t)oc * 4608 + j];
        __syncthreads();
        for (int k = t; k < 4608; k += 256) {
            int c = k & 511, tap = k >> 9;
            float v = sh[c * 9 + tap];
            unsigned short hi = f2bf(v);
            whi[(size_t)oc * 4608 + k] = hi;
            wlo[(size_t)oc * 4608 + k] = f2bf(v - bf2f(hi));
        }
    }
}

// ---------------------------------------------------------------------------
// K1m v7: LDS-staged MFMA GEMM, re-tiled for occupancy. R9's 128x128 blocks
// (64KB LDS, 320 blocks) capped at 2 blocks/CU with a 2:1 tail imbalance.
// v7: block = 128oc x 64px, 48KB LDS -> 3 blocks/CU, 640 blocks (1.5 imbal).
// Wave = 64oc x 32px (4x2 16x16 tiles). Same K-order as R9 (absmax 0.5).
// ---------------------------------------------------------------------------
__global__ __launch_bounds__(256) void k1m(const unsigned short* __restrict__ xthi,
                                           const unsigned short* __restrict__ xtlo,
                                           const unsigned short* __restrict__ whi,
                                           const unsigned short* __restrict__ wlo,
                                           float* __restrict__ pk,
                                           int cptLog, int cptm1, int cptMul, int niter)
{
    __shared__ __align__(16) unsigned short Ah[8192];   // 128oc x 64k
    __shared__ __align__(16) unsigned short Al[8192];
    __shared__ __align__(16) unsigned short Bh[4096];   // 64px x 64k
    __shared__ __align__(16) unsigned short Bl[4096];

    int t = threadIdx.x;
    int lane = t & 63, wave = t >> 6;
    int wo = wave & 1, wp = wave >> 1;   // wo: 64-oc half, wp: 32-px half
    int ocb = blockIdx.x, pxb = blockIdx.y, bs = blockIdx.z;
    int q = lane >> 4, m = lane & 15;
    int c0base = bs * cptMul;

    // staging geometry: thread -> granule g (16B) of row r0 (+32i)
    int g  = t & 7;
    int r0 = t >> 3;                     // 0..31
    int ocA[4];
    int cellB[2];
#pragma unroll
    for (int i = 0; i < 4; ++i) ocA[i] = ocb * 128 + r0 + 32 * i;
#pragma unroll
    for (int i = 0; i < 2; ++i) {
        int opx = pxb * 64 + r0 + 32 * i;
        cellB[i] = (opx < NPX) ? ((opx / 50) + 1) * 64 + (opx % 50) + 1 : 190;
    }

    f32x4 acc[8];
    f32x4 zf = {0.f, 0.f, 0.f, 0.f};
#pragma unroll
    for (int i = 0; i < 8; ++i) acc[i] = zf;

    for (int it = 0; it < niter; ++it) {
        int tap = it >> cptLog;
        int cw  = it & cptm1;
        int c0  = c0base + cw * 64;
        int t3  = (tap * 43) >> 7;                      // tap/3
        int tapoff = (t3 - 1) * 64 + (tap - t3 * 3) - 1;
        // ---- stage 48KB ----
#pragma unroll
        for (int i = 0; i < 4; ++i) {
            int rl = r0 + 32 * i;
            int la = rl * 64 + g * 8;
            size_t ga = (size_t)ocA[i] * 4608 + tap * 512 + c0 + g * 8;
            *(bf16x8*)(Ah + la) = *(const bf16x8*)(whi + ga);
            *(bf16x8*)(Al + la) = *(const bf16x8*)(wlo + ga);
        }
#pragma unroll
        for (int i = 0; i < 2; ++i) {
            int rl = r0 + 32 * i;
            int la = rl * 64 + g * 8;
            size_t gb = (size_t)(cellB[i] + tapoff) * 512 + c0 + g * 8;
            *(bf16x8*)(Bh + la) = *(const bf16x8*)(xthi + gb);
            *(bf16x8*)(Bl + la) = *(const bf16x8*)(xtlo + gb);
        }
        __syncthreads();
        // ---- compute: 2 k-steps of 32 ----
#pragma unroll
        for (int ks = 0; ks < 2; ++ks) {
            bf16x8 fah[4], fal[4], fbh[2], fbl[2];
#pragma unroll
            for (int mt = 0; mt < 4; ++mt) {
                int off = (wo * 64 + mt * 16 + m) * 64 + ks * 32 + q * 8;
                fah[mt] = *(const bf16x8*)(Ah + off);
                fal[mt] = *(const bf16x8*)(Al + off);
            }
#pragma unroll
            for (int nt = 0; nt < 2; ++nt) {
                int off = (wp * 32 + nt * 16 + m) * 64 + ks * 32 + q * 8;
                fbh[nt] = *(const bf16x8*)(Bh + off);
                fbl[nt] = *(const bf16x8*)(Bl + off);
            }
#pragma unroll
            for (int mt = 0; mt < 4; ++mt)
#pragma unroll
                for (int nt = 0; nt < 2; ++nt) {
                    f32x4 a = acc[mt * 2 + nt];
                    a = __builtin_amdgcn_mfma_f32_16x16x32_bf16(fal[mt], fbh[nt], a, 0, 0, 0);
                    a = __builtin_amdgcn_mfma_f32_16x16x32_bf16(fah[mt], fbl[nt], a, 0, 0, 0);
                    a = __builtin_amdgcn_mfma_f32_16x16x32_bf16(fah[mt], fbh[nt], a, 0, 0, 0);
                    acc[mt * 2 + nt] = a;
                }
        }
        __syncthreads();
    }
    // C/D: col(px)=lane&15, row(oc)=quad*4+reg
#pragma unroll
    for (int mt = 0; mt < 4; ++mt)
#pragma unroll
        for (int nt = 0; nt < 2; ++nt)
#pragma unroll
            for (int r = 0; r < 4; ++r) {
                int oc = ocb * 128 + wo * 64 + mt * 16 + q * 4 + r;
                int px = pxb * 64 + wp * 32 + nt * 16 + m;
                pk[((size_t)bs * 512 + oc) * 2560 + px] = acc[mt * 2 + nt][r];
            }
}

// ---------------------------------------------------------------------------
// K2a: fused k-split reduce + bias + ReLU + 1x1 heads partial GEMM.
// ---------------------------------------------------------------------------
__global__ __launch_bounds__(256) void k2a_heads(const float* __restrict__ pk, int ns,
                                                 const float* __restrict__ br,
                                                 const float* __restrict__ wcls,
                                                 const float* __restrict__ wreg,
                                                 float* __restrict__ part)
{
    __shared__ float vt[64 * 64];
    __shared__ float Wl[45 * 64];
    int t  = threadIdx.x;
    int pb = blockIdx.x;           // 0..39
    int s  = blockIdx.y;           // 0..7
    int cb = s * 64;
    for (int e = t; e < 45 * 64; e += 256) {
        int u = e >> 6, c = e & 63;
        Wl[e] = (u < 9) ? wcls[u * 512 + cb + c] : wreg[(u - 9) * 512 + cb + c];
    }
    int pxl = t & 63, ug = t >> 6;
    int px = pb * 64 + pxl;
    bool ok = px < NPX;
#pragma unroll
    for (int i = 0; i < 16; ++i) {
        int c = ug * 16 + i;       // wave-uniform
        float v = 0.f;
        if (ok) {
            size_t bidx = (size_t)(cb + c) * 2560 + px;
            v = br[cb + c];
            for (int ks = 0; ks < ns; ++ks) v += pk[(size_t)ks * 512 * 2560 + bidx];
            v = v > 0.f ? v : 0.f;
        }
        vt[c * 64 + pxl] = v;
    }
    __syncthreads();
    int ubase = ug * 12;
    int ulim  = (45 - ubase < 12) ? (45 - ubase) : 12;
    float acc[12];
#pragma unroll
    for (int j = 0; j < 12; ++j) acc[j] = 0.f;
    for (int c = 0; c < 64; ++c) {
        float v = vt[c * 64 + pxl];
#pragma unroll
        for (int j = 0; j < 12; ++j)
            acc[j] = fmaf(v, Wl[(ubase + j) * 64 + c], acc[j]);
    }
    if (ok) {
        for (int j = 0; j < ulim; ++j)
            part[((size_t)s * 45 + ubase + j) * NPX + px] = acc[j];
    }
}

// ---------------------------------------------------------------------------
// K2b: reduce partials + bias, sigmoid, decode, clip, validity, sort key.
// ---------------------------------------------------------------------------
__global__ __launch_bounds__(256) void k2b_decode(const float* __restrict__ part,
                                                  const float* __restrict__ bcls,
                                                  const float* __restrict__ breg,
                                                  AnchorBase ab,
                                                  float* __restrict__ score,
                                                  float* __restrict__ bx1, float* __restrict__ by1,
                                                  float* __restrict__ bx2, float* __restrict__ by2,
                                                  u32* __restrict__ valid,
                                                  u64* __restrict__ key)
{
    int id = blockIdx.x * 256 + threadIdx.x;
    if (id >= NANCH) return;
    int k  = id / NPX;
    int px = id - k * NPX;

    float z  = bcls[k];
    float d0 = breg[k * 4 + 0], d1 = breg[k * 4 + 1];
    float d2 = breg[k * 4 + 2], d3 = breg[k * 4 + 3];
#pragma unroll
    for (int s = 0; s < 8; ++s) {
        const float* p = part + (size_t)s * 45 * NPX;
        z  += p[(size_t)k * NPX + px];
        d0 += p[(size_t)(9 + k * 4 + 0) * NPX + px];
        d1 += p[(size_t)(9 + k * 4 + 1) * NPX + px];
        d2 += p[(size_t)(9 + k * 4 + 2) * NPX + px];
        d3 += p[(size_t)(9 + k * 4 + 3) * NPX + px];
    }
    float sc = 1.f / (1.f + expf(-z));

    int yy = px / 50, xx = px - (px / 50) * 50;
    float fx = (float)xx, fy = (float)yy;
    float ax1 = fx + ab.b[k * 4 + 0], ay1 = fy + ab.b[k * 4 + 1];
    float ax2 = fx + ab.b[k * 4 + 2], ay2 = fy + ab.b[k * 4 + 3];
    float aw = ax2 - ax1, ah = ay2 - ay1;
    float cx = ax1 + 0.5f * aw, cy = ay1 + 0.5f * ah;
    float pcx = d0 * aw + cx, pcy = d1 * ah + cy;
    float pw = expf(d2) * aw, ph = expf(d3) * ah;
    float x1 = pcx - 0.5f * pw, y1 = pcy - 0.5f * ph;
    float x2 = pcx + 0.5f * pw, y2 = pcy + 0.5f * ph;
    x1 = fminf(fmaxf(x1, 0.f), 800.f);
    y1 = fminf(fmaxf(y1, 0.f), 800.f);
    x2 = fminf(fmaxf(x2, 0.f), 800.f);
    y2 = fminf(fmaxf(y2, 0.f), 800.f);
    u32 v = ((x2 - x1) >= 16.f) && ((y2 - y1) >= 16.f);

    int f = px * 9 + k;
    score[f] = sc;
    bx1[f] = x1; by1[f] = y1; bx2[f] = x2; by2[f] = y2;
    valid[f] = v;
    u32 sb = __float_as_uint(sc);
    key[f] = ((u64)(~sb) << 32) | (u32)f;
}

// ---------------------------------------------------------------------------
// K3a v3: partial ranks, 4-way i-register-blocking (R10 — verified).
// ---------------------------------------------------------------------------
__global__ __launch_bounds__(256) void k3a_rank(const u64* __restrict__ key,
                                                u32* __restrict__ rankp)
{
    __shared__ __align__(16) u64 sk[2250];
    int t  = threadIdx.x;
    int jb = blockIdx.y;           // 0..9
    for (int e = t; e < 2250; e += 256) sk[e] = key[jb * 2250 + e];
    __syncthreads();
    int i0 = blockIdx.x * 1024 + t;
    int i1 = i0 + 256, i2 = i0 + 512, i3 = i0 + 768;
    u64 k0 = (i0 < NANCH) ? key[i0] : 0ull;
    u64 k1 = (i1 < NANCH) ? key[i1] : 0ull;
    u64 k2 = (i2 < NANCH) ? key[i2] : 0ull;
    u64 k3 = (i3 < NANCH) ? key[i3] : 0ull;
    u32 c0 = 0, c1 = 0, c2 = 0, c3 = 0;
    const ulonglong2* sk2 = (const ulonglong2*)sk;
#pragma unroll 5
    for (int j = 0; j < 1125; ++j) {
        ulonglong2 v = sk2[j];
        c0 += (v.x < k0) ? 1u : 0u;  c0 += (v.y < k0) ? 1u : 0u;
        c1 += (v.x < k1) ? 1u : 0u;  c1 += (v.y < k1) ? 1u : 0u;
        c2 += (v.x < k2) ? 1u : 0u;  c2 += (v.y < k2) ? 1u : 0u;
        c3 += (v.x < k3) ? 1u : 0u;  c3 += (v.y < k3) ? 1u : 0u;
    }
    size_t base = (size_t)jb * NANCH;
    if (i0 < NANCH) rankp[base + i0] = c0;
    if (i1 < NANCH) rankp[base + i1] = c1;
    if (i2 < NANCH) rankp[base + i2] = c2;
    if (i3 < NANCH) rankp[base + i3] = c3;
}

// ---------------------------------------------------------------------------
// K3b: sum 10 partial ranks, scatter top-10000 (+ packed float4 boxes);
// sInv[r] = 1 if invalid box.
// ---------------------------------------------------------------------------
__global__ __launch_bounds__(256) void k3b_gather(const u32* __restrict__ rankp,
                                                  const float* __restrict__ score,
                                                  const float* __restrict__ bx1, const float* __restrict__ by1,
                                                  const float* __restrict__ bx2, const float* __restrict__ by2,
                                                  const u32* __restrict__ valid,
                                                  float* __restrict__ sS,
                                                  float* __restrict__ sx1, float* __restrict__ sy1,
                                                  float* __restrict__ sx2, float* __restrict__ sy2,
                                                  float4* __restrict__ sbox4,
                                                  u32* __restrict__ sInv)
{
    int i = blockIdx.x * 256 + threadIdx.x;
    if (i >= NANCH) return;
    u32 r = 0;
#pragma unroll
    for (int c = 0; c < 10; ++c) r += rankp[(size_t)c * NANCH + i];
    if (r >= PRE_TOPK) return;
    float x1 = bx1[i], y1 = by1[i], x2 = bx2[i], y2 = by2[i];
    sS[r] = score[i];
    sx1[r] = x1; sy1[r] = y1; sx2[r] = x2; sy2[r] = y2;
    float4 b4; b4.x = x1; b4.y = y1; b4.z = x2; b4.w = y2;
    sbox4[r] = b4;
    sInv[r] = valid[i] ? 0u : 1u;
}

// ---------------------------------------------------------------------------
// K4 v5: row-per-wave suppression matrix + selfgT export.
// selfgT[g*1024 + m*256 + k*64 + b] = word (4g+m) of row of box i, where
// g = (i>>6)>>2, k = (i>>6)&3, b = i&63. Gives k5 the full 4x4 within-group
// kill matrix so it can resolve a 4-word group entirely in registers (one
// commit serialization per group instead of per word). Entries for m where
// 4g+m < wd are zero-filled (sub-diagonal); m beyond word 156 never read.
// ---------------------------------------------------------------------------
__global__ __launch_bounds__(256) void k4_mat(const float4* __restrict__ sbox4,
                                              u64* __restrict__ rows,
                                              u64* __restrict__ selfgT)
{
    int t = threadIdx.x, lane = t & 63, wave = t >> 6;
    int i = blockIdx.x * 4 + wave;
    if (i >= PRE_TOPK) return;
    float4 bi = sbox4[i];                       // wave-uniform, loaded once
    float ai = (bi.z - bi.x) * (bi.w - bi.y);
    int wd  = i >> 6;
    int gb  = wd & ~3;                          // group base word
    int g   = wd >> 2;
    int kk  = wd & 3;
    int ish = i & 63;
    u64 diagmask = ~((2ull << ish) - 1ull);     // ish=63 -> 0 (no j>i in word)
    u64* rowp = rows + (size_t)i * NWORDS;
    if (lane == 0) {
        for (int w0 = gb; w0 < wd; ++w0)        // sub-diagonal group words = 0
            selfgT[(size_t)g * 1024 + (w0 - gb) * 256 + kk * 64 + ish] = 0ull;
    }
    for (int w = wd; w < 157; ++w) {
        float4 bj = sbox4[(w << 6) + lane];     // coalesced dwordx4
        float xx1 = fmaxf(bi.x, bj.x);
        float yy1 = fmaxf(bi.y, bj.y);
        float xx2 = fminf(bi.z, bj.z);
        float yy2 = fminf(bi.w, bj.w);
        float iw = fmaxf(xx2 - xx1, 0.f);
        float ih = fmaxf(yy2 - yy1, 0.f);
        float inter = iw * ih;
        float aj = (bj.z - bj.x) * (bj.w - bj.y);
        float uni = ai + aj - inter;
        u64 b = __ballot(inter > 0.7f * uni);
        if (w == wd)  b &= diagmask;
        if (w == 156) b &= 0xFFFFull;
        if (lane == 0) {
            rowp[w] = b;
            if (w < gb + 4)
                selfgT[(size_t)g * 1024 + (w - gb) * 256 + kk * 64 + ish] = b;
        }
    }
}

// ---------------------------------------------------------------------------
// K5 v7: 4-word-group greedy NMS scan.
// R14 diagnosis of v6 (65us): ~157 serialization points (one per word), each
// exposing ~700-900cyc of commit-load latency before the next word's r-state
// readlane. v7 amortizes: resolve 4 words (256 boxes) per iteration using the
// precomputed selfgT 4x4 kill matrix (depth-2 register ring, like v6's selfw
// ring), then ONE batched commit region per group -> ~40 waits instead of 157.
// Slot-skip: once the scan passes word 64/128, slot0/slot1 of kept rows are
// dead (never read again) -> ~27% fewer commit loads.
// Falsification: if k5 >= 60us, the <=63-outstanding-load floor dominates and
// k5 is structurally done.
// ---------------------------------------------------------------------------
__global__ __launch_bounds__(64, 1) void k5_scan(const u64* __restrict__ rows,
                                              const u64* __restrict__ selfgT,
                                              const u32* __restrict__ sInv,
                                              const float* __restrict__ sS,
                                              const float* __restrict__ sx1, const float* __restrict__ sy1,
                                              const float* __restrict__ sx2, const float* __restrict__ sy2,
                                              float* __restrict__ out)
{
    __shared__ int keptList[2000];
    __shared__ int kcnt;
    int l = threadIdx.x;
    auto bw = [&](int w) -> u64 {
        const uint4* p = (const uint4*)(sInv + (size_t)w * 64);
        u64 v = 0;
#pragma unroll
        for (int j = 0; j < 16; ++j) {
            uint4 q = p[j];
            v |= ((u64)(q.x != 0) << (j * 4))     | ((u64)(q.y != 0) << (j * 4 + 1))
               | ((u64)(q.z != 0) << (j * 4 + 2)) | ((u64)(q.w != 0) << (j * 4 + 3));
        }
        return v;
    };
    auto rdl = [&](u64 v, int src) -> u64 {
        u32 lo = __builtin_amdgcn_readlane((u32)v, src);
        u32 hi = __builtin_amdgcn_readlane((u32)(v >> 32), src);
        return ((u64)hi << 32) | lo;
    };
    auto ldsg = [&](int g, int m, int k) -> u64 {
        return selfgT[(size_t)g * 1024 + m * 256 + k * 64 + l];
    };
    u64 r0 = bw(l);
    u64 r1 = bw(64 + l);
    u64 r2 = (l < 32) ? bw(128 + l) : ~0ull;

    auto avInit = [&](int w) -> u64 {
        if (w > 156) return 0ull;
        int slot = w >> 6, owner = w & 63;
        u64 val = (slot == 0) ? r0 : (slot == 1) ? r1 : r2;
        u64 rw = rdl(val, owner);
        u64 wmask = (w == 156) ? 0xFFFFull : ~0ull;
        return (~rw) & wmask;
    };

    // selfg ring: cur c{m}{k}, next n{m}{k}; m = target word, k = source word.
    u64 c00 = ldsg(0,0,0), c01 = ldsg(0,0,1), c02 = ldsg(0,0,2), c03 = ldsg(0,0,3);
    u64 c10 = ldsg(0,1,0), c11 = ldsg(0,1,1), c12 = ldsg(0,1,2), c13 = ldsg(0,1,3);
    u64 c20 = ldsg(0,2,0), c21 = ldsg(0,2,1), c22 = ldsg(0,2,2), c23 = ldsg(0,2,3);
    u64 c30 = ldsg(0,3,0), c31 = ldsg(0,3,1), c32 = ldsg(0,3,2), c33 = ldsg(0,3,3);
    u64 n00 = ldsg(1,0,0), n01 = ldsg(1,0,1), n02 = ldsg(1,0,2), n03 = ldsg(1,0,3);
    u64 n10 = ldsg(1,1,0), n11 = ldsg(1,1,1), n12 = ldsg(1,1,2), n13 = ldsg(1,1,3);
    u64 n20 = ldsg(1,2,0), n21 = ldsg(1,2,1), n22 = ldsg(1,2,2), n23 = ldsg(1,2,3);
    u64 n30 = ldsg(1,3,0), n31 = ldsg(1,3,1), n32 = ldsg(1,3,2), n33 = ldsg(1,3,3);

    int cnt = 0;
    bool done = false;
    for (int g = 0; g < 40 && !done; ++g) {
        int wb = g << 2;
        u64 av0 = avInit(wb + 0);
        u64 av1 = avInit(wb + 1);
        u64 av2 = avInit(wb + 2);
        u64 av3 = avInit(wb + 3);
        u64 km0 = 0, km1 = 0, km2 = 0, km3 = 0;
        // ---- register-only 4-word greedy resolve (index order) ----
        while (av0) {
            int b = __builtin_ctzll((unsigned long long)av0);
            u64 s0 = rdl(c00, b), s1 = rdl(c10, b), s2 = rdl(c20, b), s3 = rdl(c30, b);
            km0 |= 1ull << b;
            av0 = (av0 & (av0 - 1)) & ~s0;
            av1 &= ~s1; av2 &= ~s2; av3 &= ~s3;
        }
        while (av1) {
            int b = __builtin_ctzll((unsigned long long)av1);
            u64 s1 = rdl(c11, b), s2 = rdl(c21, b), s3 = rdl(c31, b);
            km1 |= 1ull << b;
            av1 = (av1 & (av1 - 1)) & ~s1;
            av2 &= ~s2; av3 &= ~s3;
        }
        while (av2) {
            int b = __builtin_ctzll((unsigned long long)av2);
            u64 s2 = rdl(c22, b), s3 = rdl(c32, b);
            km2 |= 1ull << b;
            av2 = (av2 & (av2 - 1)) & ~s2;
            av3 &= ~s3;
        }
        while (av3) {
            int b = __builtin_ctzll((unsigned long long)av3);
            u64 s3 = rdl(c33, b);
            km3 |= 1ull << b;
            av3 = (av3 & (av3 - 1)) & ~s3;
        }
        // ---- commit: gather kept (index order), batch-32 load regions ----
        bool need0 = (wb + 4) < 64;    // slot0 read by any future group?
        bool need1 = (wb + 4) < 128;
        int bsx[32];
        int nb = 0;
        auto flush = [&]() {
            if (nb == 0) return;
            u64 a0 = 0, a1 = 0, a2 = 0;
#pragma unroll
            for (int u = 0; u < 32; ++u) {
                if (u < nb) {
                    const u64* rp = rows + (size_t)bsx[u] * NWORDS;
                    if (need0) a0 |= rp[l];
                    if (need1) a1 |= rp[64 + l];
                    if (l < 32) a2 |= rp[128 + l];
                }
            }
            if (need0) r0 |= a0;
            if (need1) r1 |= a1;
            r2 |= a2;
            nb = 0;
        };
#pragma unroll
        for (int kk = 0; kk < 4; ++kk) {
            u64 mask = (kk == 0) ? km0 : (kk == 1) ? km1 : (kk == 2) ? km2 : km3;
            int wbase = (wb + kk) << 6;
            while (mask) {
                int b = __builtin_ctzll((unsigned long long)mask);
                mask &= mask - 1;
                int idx = wbase + b;
                if (l == 0 && cnt < 2000) keptList[cnt] = idx;
                ++cnt;
                bsx[nb++] = idx;
                if (nb == 32) flush();
                if (cnt >= 2000) { done = true; break; }
            }
            if (done) break;
        }
        if (!done) {
            flush();
            // ---- rotate selfg ring, prefetch group g+2 ----
            c00 = n00; c01 = n01; c02 = n02; c03 = n03;
            c10 = n10; c11 = n11; c12 = n12; c13 = n13;
            c20 = n20; c21 = n21; c22 = n22; c23 = n23;
            c30 = n30; c31 = n31; c32 = n32; c33 = n33;
            int gn = g + 2;
            if (gn < 40) {
                n00 = ldsg(gn,0,0); n01 = ldsg(gn,0,1); n02 = ldsg(gn,0,2); n03 = ldsg(gn,0,3);
                n10 = ldsg(gn,1,0); n11 = ldsg(gn,1,1); n12 = ldsg(gn,1,2); n13 = ldsg(gn,1,3);
                n20 = ldsg(gn,2,0); n21 = ldsg(gn,2,1); n22 = ldsg(gn,2,2); n23 = ldsg(gn,2,3);
                n30 = ldsg(gn,3,0); n31 = ldsg(gn,3,1); n32 = ldsg(gn,3,2); n33 = ldsg(gn,3,3);
            }
        }
    }
    if (l == 0) kcnt = (cnt < 2000) ? cnt : 2000;
    __syncthreads();
    int K = kcnt;
    for (int r = l; r < 2000; r += 64) {
        if (r < K) {
            int j = keptList[r];
            out[r * 4 + 0] = sx1[j];
            out[r * 4 + 1] = sy1[j];
            out[r * 4 + 2] = sx2[j];
            out[r * 4 + 3] = sy2[j];
            out[8000 + r]  = sS[j];
        } else {
            out[r * 4 + 0] = 0.f; out[r * 4 + 1] = 0.f;
            out[r * 4 + 2] = 0.f; out[r * 4 + 3] = 0.f;
            out[8000 + r]  = 0.f;
        }
    }
}

// ---------------------------------------------------------------------------
extern "C" void kernel_launch(void* const* d_in, const int* in_sizes, int n_in,
                              void* d_out, int out_size, void* d_ws, size_t ws_size,
                              hipStream_t stream)
{
    (void)in_sizes; (void)n_in; (void)out_size;
    const float* feat = (const float*)d_in[1];
    const float* wrpn = (const float*)d_in[3];
    const float* brpn = (const float*)d_in[4];
    const float* wcls = (const float*)d_in[5];
    const float* bcls = (const float*)d_in[6];
    const float* wreg = (const float*)d_in[7];
    const float* breg = (const float*)d_in[8];
    float* out = (float*)d_out;

    // K-split factor by workspace budget. need(ns) = ns*512*2560*4 + 16,252,928.
    int ns = (ws_size >= 58195968) ? 8 : (ws_size >= 37224448) ? 4 : 2;
    int cpt     = 8 / ns;                 // 64c-chunks per tap per z-slice
    int cptLog  = (ns == 2) ? 2 : (ns == 4) ? 1 : 0;
    int cptm1   = cpt - 1;
    int cptMul  = cpt * 64;               // c0base = bs * cptMul
    int niter   = 9 * cpt;
    size_t pkB = (size_t)ns * 512 * 2560 * 4;

    char* ws = (char*)d_ws;
    // Live ranges:
    //   [0,pkB)            pk     k1m..k2a
    //   [pkB,pkB+16.25M)   Xt+W   kprep..k1m; then smalls (k2a+), part
    //                      (k2a..k2b), rows+selfgT (memset/k4..k5) share offsets.
    float* pk = (float*)ws;
    unsigned short* Xthi = (unsigned short*)(ws + pkB);
    unsigned short* Xtlo = Xthi + (size_t)52 * 64 * 512;
    unsigned short* Whi  = (unsigned short*)(ws + pkB + 6815744);
    unsigned short* Wlo  = Whi + (size_t)512 * 4608;

    char* sm = ws + pkB;
    float* score = (float*)(sm + 0);             // 90,000
    float* bx1   = (float*)(sm + 90000);
    float* by1   = (float*)(sm + 180000);
    float* bx2   = (float*)(sm + 270000);
    float* by2   = (float*)(sm + 360000);
    u32*   valid = (u32*)  (sm + 450000);        // 90,000
    u64*   key   = (u64*)  (sm + 540000);        // 180,000
    u32*   rankp = (u32*)  (sm + 720000);        // 900,000 (10 chunks)
    float* sS    = (float*)(sm + 1620000);       // 40,000
    float* sx1   = (float*)(sm + 1660000);
    float* sy1   = (float*)(sm + 1700000);
    float* sx2   = (float*)(sm + 1740000);
    float* sy2   = (float*)(sm + 1780000);
    u32*   sInv  = (u32*)  (sm + 1820000);       // 40,960
    float4* sbox4= (float4*)(sm + 1942880);      // 163,840 (10240 entries)
    float* part  = (float*)(sm + 2106720);       // 3,600,000 (k2a..k2b)
    u64*   rows  = (u64*)  (sm + 2106720);       // 12,800,000 (k4..k5) -> ends sm+14,906,720
    u64*   selfgT= (u64*)  (sm + 14906720);      // 327,680 (k4..k5) -> ends sm+15,234,400 < 16.25M
    // peak footprint = pkB + 16,252,928 (ns=4 -> 37.2 MB, proven available)

    AnchorBase ab;
    {
        const float scales[3] = {128.f, 256.f, 512.f};
        const float aspect[3] = {0.5f, 1.f, 2.f};
        for (int ai = 0; ai < 3; ++ai) {
            float hr = sqrtf(aspect[ai]);
            float wratio = 1.0f / hr;
            for (int si = 0; si < 3; ++si) {
                float wsz = wratio * scales[si];
                float hsz = hr * scales[si];
                int a = ai * 3 + si;
                ab.b[a * 4 + 0] = rintf(-wsz / 2.0f);
                ab.b[a * 4 + 1] = rintf(-hsz / 2.0f);
                ab.b[a * 4 + 2] = rintf( wsz / 2.0f);
                ab.b[a * 4 + 3] = rintf( hsz / 2.0f);
            }
        }
    }

    kprep    <<<928, 256, 0, stream>>>(feat, wrpn, Xthi, Xtlo, Whi, Wlo);
    k1m      <<<dim3(4, 40, ns), 256, 0, stream>>>(Xthi, Xtlo, Whi, Wlo, pk,
                                                   cptLog, cptm1, cptMul, niter);
    k2a_heads<<<dim3(40, 8), 256, 0, stream>>>(pk, ns, brpn, wcls, wreg, part);
    k2b_decode<<<88, 256, 0, stream>>>(part, bcls, breg, ab, score, bx1, by1, bx2, by2, valid, key);
    k3a_rank <<<dim3(22, 10), 256, 0, stream>>>(key, rankp);
    k3b_gather<<<88, 256, 0, stream>>>(rankp, score, bx1, by1, bx2, by2, valid,
                                       sS, sx1, sy1, sx2, sy2, sbox4, sInv);
    hipMemsetAsync(rows, 0, (size_t)PRE_TOPK * NWORDS * 8, stream);   // sub-diagonal + tail words
    k4_mat   <<<2500, 256, 0, stream>>>(sbox4, rows, selfgT);
    k5_scan  <<<1, 64, 0, stream>>>(rows, selfgT, sInv, sS, sx1, sy1, sx2, sy2, out);
}

// Round 5
// 384.937 us; speedup vs baseline: 1.0105x; 1.0105x over previous
//
#include <hip/hip_runtime.h>
#include <cmath>
#include <cstdint>
#include <cstddef>

typedef unsigned long long u64;
typedef unsigned int u32;

#define NPX   2500
#define NANCH 22500
#define PRE_TOPK 10000
#define NWORDS 160      // 160*64 = 10240 bits per NMS row

struct AnchorBase { float b[36]; };

typedef __attribute__((ext_vector_type(8))) short bf16x8;
typedef __attribute__((ext_vector_type(4))) float f32x4;

__device__ inline unsigned short f2bf(float f) {
    u32 u = __float_as_uint(f);
    u32 r = u + 0x7fffu + ((u >> 16) & 1u);
    return (unsigned short)(r >> 16);
}
__device__ inline float bf2f(unsigned short h) {
    return __uint_as_float(((u32)h) << 16);
}

// ---------------------------------------------------------------------------
// KPREP: fused input prep (Xt bf16 hi/lo padded grid; W' bf16 hi/lo).
// ---------------------------------------------------------------------------
__global__ __launch_bounds__(256) void kprep(const float* __restrict__ feat,
                                             const float* __restrict__ wr,
                                             unsigned short* __restrict__ xthi,
                                             unsigned short* __restrict__ xtlo,
                                             unsigned short* __restrict__ whi,
                                             unsigned short* __restrict__ wlo)
{
    __shared__ float sh[4608];
    int bid = blockIdx.x;
    int t = threadIdx.x;
    if (bid < 416) {
        float (*tile)[65] = (float(*)[65])sh;
        int gr = bid >> 3;          // grid row 0..51
        int cc = bid & 7;           // c-chunk
        int tx = t & 63, ty = t >> 6;
        int y = gr - 1;
        bool rowok = (gr >= 1) && (gr <= 50);
#pragma unroll
        for (int i = 0; i < 16; ++i) {
            int c = i * 4 + ty;
            tile[c][tx] = (rowok && tx < 50)
                        ? feat[(size_t)(cc * 64 + c) * NPX + y * 50 + tx] : 0.f;
        }
        __syncthreads();
#pragma unroll
        for (int i = 0; i < 16; ++i) {
            int xp = i * 4 + ty;
            int cell = gr * 64 + xp;
            bool ok = rowok && xp >= 1 && xp <= 50;
            float v = ok ? tile[tx][xp - 1] : 0.f;
            unsigned short hi = f2bf(v);
            xthi[(size_t)cell * 512 + cc * 64 + tx] = hi;
            xtlo[(size_t)cell * 512 + cc * 64 + tx] = f2bf(v - bf2f(hi));
        }
    } else {
        int oc = bid - 416;         // 0..511
        for (int j = t; j < 4608; j += 256) sh[j] = wr[(size_t)oc * 4608 + j];
        __syncthreads();
        for (int k = t; k < 4608; k += 256) {
            int c = k & 511, tap = k >> 9;
            float v = sh[c * 9 + tap];
            unsigned short hi = f2bf(v);
            whi[(size_t)oc * 4608 + k] = hi;
            wlo[(size_t)oc * 4608 + k] = f2bf(v - bf2f(hi));
        }
    }
}

// ---------------------------------------------------------------------------
// K1m v7: LDS-staged MFMA GEMM, re-tiled for occupancy. R9's 128x128 blocks
// (64KB LDS, 320 blocks) capped at 2 blocks/CU with a 2:1 tail imbalance.
// v7: block = 128oc x 64px, 48KB LDS -> 3 blocks/CU, 640 blocks (1.5 imbal).
// Wave = 64oc x 32px (4x2 16x16 tiles). Same K-order as R9 (absmax 0.5).
// ---------------------------------------------------------------------------
__global__ __launch_bounds__(256) void k1m(const unsigned short* __restrict__ xthi,
                                           const unsigned short* __restrict__ xtlo,
                                           const unsigned short* __restrict__ whi,
                                           const unsigned short* __restrict__ wlo,
                                           float* __restrict__ pk,
                                           int cptLog, int cptm1, int cptMul, int niter)
{
    __shared__ __align__(16) unsigned short Ah[8192];   // 128oc x 64k
    __shared__ __align__(16) unsigned short Al[8192];
    __shared__ __align__(16) unsigned short Bh[4096];   // 64px x 64k
    __shared__ __align__(16) unsigned short Bl[4096];

    int t = threadIdx.x;
    int lane = t & 63, wave = t >> 6;
    int wo = wave & 1, wp = wave >> 1;   // wo: 64-oc half, wp: 32-px half
    int ocb = blockIdx.x, pxb = blockIdx.y, bs = blockIdx.z;
    int q = lane >> 4, m = lane & 15;
    int c0base = bs * cptMul;

    // staging geometry: thread -> granule g (16B) of row r0 (+32i)
    int g  = t & 7;
    int r0 = t >> 3;                     // 0..31
    int ocA[4];
    int cellB[2];
#pragma unroll
    for (int i = 0; i < 4; ++i) ocA[i] = ocb * 128 + r0 + 32 * i;
#pragma unroll
    for (int i = 0; i < 2; ++i) {
        int opx = pxb * 64 + r0 + 32 * i;
        cellB[i] = (opx < NPX) ? ((opx / 50) + 1) * 64 + (opx % 50) + 1 : 190;
    }

    f32x4 acc[8];
    f32x4 zf = {0.f, 0.f, 0.f, 0.f};
#pragma unroll
    for (int i = 0; i < 8; ++i) acc[i] = zf;

    for (int it = 0; it < niter; ++it) {
        int tap = it >> cptLog;
        int cw  = it & cptm1;
        int c0  = c0base + cw * 64;
        int t3  = (tap * 43) >> 7;                      // tap/3
        int tapoff = (t3 - 1) * 64 + (tap - t3 * 3) - 1;
        // ---- stage 48KB ----
#pragma unroll
        for (int i = 0; i < 4; ++i) {
            int rl = r0 + 32 * i;
            int la = rl * 64 + g * 8;
            size_t ga = (size_t)ocA[i] * 4608 + tap * 512 + c0 + g * 8;
            *(bf16x8*)(Ah + la) = *(const bf16x8*)(whi + ga);
            *(bf16x8*)(Al + la) = *(const bf16x8*)(wlo + ga);
        }
#pragma unroll
        for (int i = 0; i < 2; ++i) {
            int rl = r0 + 32 * i;
            int la = rl * 64 + g * 8;
            size_t gb = (size_t)(cellB[i] + tapoff) * 512 + c0 + g * 8;
            *(bf16x8*)(Bh + la) = *(const bf16x8*)(xthi + gb);
            *(bf16x8*)(Bl + la) = *(const bf16x8*)(xtlo + gb);
        }
        __syncthreads();
        // ---- compute: 2 k-steps of 32 ----
#pragma unroll
        for (int ks = 0; ks < 2; ++ks) {
            bf16x8 fah[4], fal[4], fbh[2], fbl[2];
#pragma unroll
            for (int mt = 0; mt < 4; ++mt) {
                int off = (wo * 64 + mt * 16 + m) * 64 + ks * 32 + q * 8;
                fah[mt] = *(const bf16x8*)(Ah + off);
                fal[mt] = *(const bf16x8*)(Al + off);
            }
#pragma unroll
            for (int nt = 0; nt < 2; ++nt) {
                int off = (wp * 32 + nt * 16 + m) * 64 + ks * 32 + q * 8;
                fbh[nt] = *(const bf16x8*)(Bh + off);
                fbl[nt] = *(const bf16x8*)(Bl + off);
            }
#pragma unroll
            for (int mt = 0; mt < 4; ++mt)
#pragma unroll
                for (int nt = 0; nt < 2; ++nt) {
                    f32x4 a = acc[mt * 2 + nt];
                    a = __builtin_amdgcn_mfma_f32_16x16x32_bf16(fal[mt], fbh[nt], a, 0, 0, 0);
                    a = __builtin_amdgcn_mfma_f32_16x16x32_bf16(fah[mt], fbl[nt], a, 0, 0, 0);
                    a = __builtin_amdgcn_mfma_f32_16x16x32_bf16(fah[mt], fbh[nt], a, 0, 0, 0);
                    acc[mt * 2 + nt] = a;
                }
        }
        __syncthreads();
    }
    // C/D: col(px)=lane&15, row(oc)=quad*4+reg
#pragma unroll
    for (int mt = 0; mt < 4; ++mt)
#pragma unroll
        for (int nt = 0; nt < 2; ++nt)
#pragma unroll
            for (int r = 0; r < 4; ++r) {
                int oc = ocb * 128 + wo * 64 + mt * 16 + q * 4 + r;
                int px = pxb * 64 + wp * 32 + nt * 16 + m;
                pk[((size_t)bs * 512 + oc) * 2560 + px] = acc[mt * 2 + nt][r];
            }
}

// ---------------------------------------------------------------------------
// K2a: fused k-split reduce + bias + ReLU + 1x1 heads partial GEMM.
// ---------------------------------------------------------------------------
__global__ __launch_bounds__(256) void k2a_heads(const float* __restrict__ pk, int ns,
                                                 const float* __restrict__ br,
                                                 const float* __restrict__ wcls,
                                                 const float* __restrict__ wreg,
                                                 float* __restrict__ part)
{
    __shared__ float vt[64 * 64];
    __shared__ float Wl[45 * 64];
    int t  = threadIdx.x;
    int pb = blockIdx.x;           // 0..39
    int s  = blockIdx.y;           // 0..7
    int cb = s * 64;
    for (int e = t; e < 45 * 64; e += 256) {
        int u = e >> 6, c = e & 63;
        Wl[e] = (u < 9) ? wcls[u * 512 + cb + c] : wreg[(u - 9) * 512 + cb + c];
    }
    int pxl = t & 63, ug = t >> 6;
    int px = pb * 64 + pxl;
    bool ok = px < NPX;
#pragma unroll
    for (int i = 0; i < 16; ++i) {
        int c = ug * 16 + i;       // wave-uniform
        float v = 0.f;
        if (ok) {
            size_t bidx = (size_t)(cb + c) * 2560 + px;
            v = br[cb + c];
            for (int ks = 0; ks < ns; ++ks) v += pk[(size_t)ks * 512 * 2560 + bidx];
            v = v > 0.f ? v : 0.f;
        }
        vt[c * 64 + pxl] = v;
    }
    __syncthreads();
    int ubase = ug * 12;
    int ulim  = (45 - ubase < 12) ? (45 - ubase) : 12;
    float acc[12];
#pragma unroll
    for (int j = 0; j < 12; ++j) acc[j] = 0.f;
    for (int c = 0; c < 64; ++c) {
        float v = vt[c * 64 + pxl];
#pragma unroll
        for (int j = 0; j < 12; ++j)
            acc[j] = fmaf(v, Wl[(ubase + j) * 64 + c], acc[j]);
    }
    if (ok) {
        for (int j = 0; j < ulim; ++j)
            part[((size_t)s * 45 + ubase + j) * NPX + px] = acc[j];
    }
}

// ---------------------------------------------------------------------------
// K2b: reduce partials + bias, sigmoid, decode, clip, validity, sort key.
// ---------------------------------------------------------------------------
__global__ __launch_bounds__(256) void k2b_decode(const float* __restrict__ part,
                                                  const float* __restrict__ bcls,
                                                  const float* __restrict__ breg,
                                                  AnchorBase ab,
                                                  float* __restrict__ score,
                                                  float* __restrict__ bx1, float* __restrict__ by1,
                                                  float* __restrict__ bx2, float* __restrict__ by2,
                                                  u32* __restrict__ valid,
                                                  u64* __restrict__ key)
{
    int id = blockIdx.x * 256 + threadIdx.x;
    if (id >= NANCH) return;
    int k  = id / NPX;
    int px = id - k * NPX;

    float z  = bcls[k];
    float d0 = breg[k * 4 + 0], d1 = breg[k * 4 + 1];
    float d2 = breg[k * 4 + 2], d3 = breg[k * 4 + 3];
#pragma unroll
    for (int s = 0; s < 8; ++s) {
        const float* p = part + (size_t)s * 45 * NPX;
        z  += p[(size_t)k * NPX + px];
        d0 += p[(size_t)(9 + k * 4 + 0) * NPX + px];
        d1 += p[(size_t)(9 + k * 4 + 1) * NPX + px];
        d2 += p[(size_t)(9 + k * 4 + 2) * NPX + px];
        d3 += p[(size_t)(9 + k * 4 + 3) * NPX + px];
    }
    float sc = 1.f / (1.f + expf(-z));

    int yy = px / 50, xx = px - (px / 50) * 50;
    float fx = (float)xx, fy = (float)yy;
    float ax1 = fx + ab.b[k * 4 + 0], ay1 = fy + ab.b[k * 4 + 1];
    float ax2 = fx + ab.b[k * 4 + 2], ay2 = fy + ab.b[k * 4 + 3];
    float aw = ax2 - ax1, ah = ay2 - ay1;
    float cx = ax1 + 0.5f * aw, cy = ay1 + 0.5f * ah;
    float pcx = d0 * aw + cx, pcy = d1 * ah + cy;
    float pw = expf(d2) * aw, ph = expf(d3) * ah;
    float x1 = pcx - 0.5f * pw, y1 = pcy - 0.5f * ph;
    float x2 = pcx + 0.5f * pw, y2 = pcy + 0.5f * ph;
    x1 = fminf(fmaxf(x1, 0.f), 800.f);
    y1 = fminf(fmaxf(y1, 0.f), 800.f);
    x2 = fminf(fmaxf(x2, 0.f), 800.f);
    y2 = fminf(fmaxf(y2, 0.f), 800.f);
    u32 v = ((x2 - x1) >= 16.f) && ((y2 - y1) >= 16.f);

    int f = px * 9 + k;
    score[f] = sc;
    bx1[f] = x1; by1[f] = y1; bx2[f] = x2; by2[f] = y2;
    valid[f] = v;
    u32 sb = __float_as_uint(sc);
    key[f] = ((u64)(~sb) << 32) | (u32)f;
}

// ---------------------------------------------------------------------------
// K3a v3: partial ranks, 4-way i-register-blocking (R10 — verified).
// ---------------------------------------------------------------------------
__global__ __launch_bounds__(256) void k3a_rank(const u64* __restrict__ key,
                                                u32* __restrict__ rankp)
{
    __shared__ __align__(16) u64 sk[2250];
    int t  = threadIdx.x;
    int jb = blockIdx.y;           // 0..9
    for (int e = t; e < 2250; e += 256) sk[e] = key[jb * 2250 + e];
    __syncthreads();
    int i0 = blockIdx.x * 1024 + t;
    int i1 = i0 + 256, i2 = i0 + 512, i3 = i0 + 768;
    u64 k0 = (i0 < NANCH) ? key[i0] : 0ull;
    u64 k1 = (i1 < NANCH) ? key[i1] : 0ull;
    u64 k2 = (i2 < NANCH) ? key[i2] : 0ull;
    u64 k3 = (i3 < NANCH) ? key[i3] : 0ull;
    u32 c0 = 0, c1 = 0, c2 = 0, c3 = 0;
    const ulonglong2* sk2 = (const ulonglong2*)sk;
#pragma unroll 5
    for (int j = 0; j < 1125; ++j) {
        ulonglong2 v = sk2[j];
        c0 += (v.x < k0) ? 1u : 0u;  c0 += (v.y < k0) ? 1u : 0u;
        c1 += (v.x < k1) ? 1u : 0u;  c1 += (v.y < k1) ? 1u : 0u;
        c2 += (v.x < k2) ? 1u : 0u;  c2 += (v.y < k2) ? 1u : 0u;
        c3 += (v.x < k3) ? 1u : 0u;  c3 += (v.y < k3) ? 1u : 0u;
    }
    size_t base = (size_t)jb * NANCH;
    if (i0 < NANCH) rankp[base + i0] = c0;
    if (i1 < NANCH) rankp[base + i1] = c1;
    if (i2 < NANCH) rankp[base + i2] = c2;
    if (i3 < NANCH) rankp[base + i3] = c3;
}

// ---------------------------------------------------------------------------
// K3b: sum 10 partial ranks, scatter top-10000 (+ packed float4 boxes);
// sInv[r] = 1 if invalid box.
// ---------------------------------------------------------------------------
__global__ __launch_bounds__(256) void k3b_gather(const u32* __restrict__ rankp,
                                                  const float* __restrict__ score,
                                                  const float* __restrict__ bx1, const float* __restrict__ by1,
                                                  const float* __restrict__ bx2, const float* __restrict__ by2,
                                                  const u32* __restrict__ valid,
                                                  float* __restrict__ sS,
                                                  float* __restrict__ sx1, float* __restrict__ sy1,
                                                  float* __restrict__ sx2, float* __restrict__ sy2,
                                                  float4* __restrict__ sbox4,
                                                  u32* __restrict__ sInv)
{
    int i = blockIdx.x * 256 + threadIdx.x;
    if (i >= NANCH) return;
    u32 r = 0;
#pragma unroll
    for (int c = 0; c < 10; ++c) r += rankp[(size_t)c * NANCH + i];
    if (r >= PRE_TOPK) return;
    float x1 = bx1[i], y1 = by1[i], x2 = bx2[i], y2 = by2[i];
    sS[r] = score[i];
    sx1[r] = x1; sy1[r] = y1; sx2[r] = x2; sy2[r] = y2;
    float4 b4; b4.x = x1; b4.y = y1; b4.z = x2; b4.w = y2;
    sbox4[r] = b4;
    sInv[r] = valid[i] ? 0u : 1u;
}

// ---------------------------------------------------------------------------
// K4 v4: row-per-wave suppression matrix (R10 — verified, ~20us).
// ---------------------------------------------------------------------------
__global__ __launch_bounds__(256) void k4_mat(const float4* __restrict__ sbox4,
                                              u64* __restrict__ rows,
                                              u64* __restrict__ selfw)
{
    int t = threadIdx.x, lane = t & 63, wave = t >> 6;
    int i = blockIdx.x * 4 + wave;
    if (i >= PRE_TOPK) return;
    float4 bi = sbox4[i];                       // wave-uniform, loaded once
    float ai = (bi.z - bi.x) * (bi.w - bi.y);
    int wd  = i >> 6;
    int ish = i & 63;
    u64 diagmask = ~((2ull << ish) - 1ull);     // ish=63 -> 0 (no j>i in word)
    u64* rowp = rows + (size_t)i * NWORDS;
    for (int w = wd; w < 157; ++w) {
        float4 bj = sbox4[(w << 6) + lane];     // coalesced dwordx4
        float xx1 = fmaxf(bi.x, bj.x);
        float yy1 = fmaxf(bi.y, bj.y);
        float xx2 = fminf(bi.z, bj.z);
        float yy2 = fminf(bi.w, bj.w);
        float iw = fmaxf(xx2 - xx1, 0.f);
        float ih = fmaxf(yy2 - yy1, 0.f);
        float inter = iw * ih;
        float aj = (bj.z - bj.x) * (bj.w - bj.y);
        float uni = ai + aj - inter;
        u64 b = __ballot(inter > 0.7f * uni);
        if (w == wd)  b &= diagmask;
        if (w == 156) b &= 0xFFFFull;
        if (lane == 0) {
            rowp[w] = b;
            if (w == wd) selfw[i] = b;
        }
    }
}

// ---------------------------------------------------------------------------
// K5 v8: v6 (R3-verified, 65.4us) + dead-slot skip in commit.
// R15 post-mortem of v7 (88.9us, REGRESSION): cutting serialization points
// 157->40 via 4-word-group resolve made it SLOWER (+3 forward-kill readlanes
// per kept, +16 ring loads/group, 2 flush waits/group, bigger scratch bsx).
// The per-word wait model was wrong -> scan structure is at its local optimum;
// restructures abandoned. v8 = exact v6 plus ONE wave-uniform cut: after word
// 63, slot0 of kept rows is never read again (avInit reads slot w'>>6 only
// for w' > w); after word 127, slot1 dead too. Skip those loads and ORs.
// Commit loads drop 3.0 -> ~2.2 per kept (-27%).
// Falsification: if k5 >= 63us, commit loads aren't binding -> k5 is done.
// ---------------------------------------------------------------------------
__global__ __launch_bounds__(64) void k5_scan(const u64* __restrict__ rows,
                                              const u64* __restrict__ selfw,
                                              const u32* __restrict__ sInv,
                                              const float* __restrict__ sS,
                                              const float* __restrict__ sx1, const float* __restrict__ sy1,
                                              const float* __restrict__ sx2, const float* __restrict__ sy2,
                                              float* __restrict__ out)
{
    __shared__ int keptList[2000];
    __shared__ int kcnt;
    int l = threadIdx.x;
    auto bw = [&](int w) -> u64 {
        const uint4* p = (const uint4*)(sInv + (size_t)w * 64);
        u64 v = 0;
#pragma unroll
        for (int j = 0; j < 16; ++j) {
            uint4 q = p[j];
            v |= ((u64)(q.x != 0) << (j * 4))     | ((u64)(q.y != 0) << (j * 4 + 1))
               | ((u64)(q.z != 0) << (j * 4 + 2)) | ((u64)(q.w != 0) << (j * 4 + 3));
        }
        return v;
    };
    // 64-bit uniform readlane helper (2x v_readlane_b32)
    auto rdlane64 = [&](u64 v, int src) -> u64 {
        u32 lo = __builtin_amdgcn_readlane((u32)v, src);
        u32 hi = __builtin_amdgcn_readlane((u32)(v >> 32), src);
        return ((u64)hi << 32) | lo;
    };
    u64 r0 = bw(l);
    u64 r1 = bw(64 + l);
    u64 r2 = (l < 32) ? bw(128 + l) : ~0ull;

    // depth-8 selfw prefetch ring in named registers (static, no array)
    u64 s0 = selfw[(size_t)0 * 64 + l];
    u64 s1 = selfw[(size_t)1 * 64 + l];
    u64 s2 = selfw[(size_t)2 * 64 + l];
    u64 s3 = selfw[(size_t)3 * 64 + l];
    u64 s4 = selfw[(size_t)4 * 64 + l];
    u64 s5 = selfw[(size_t)5 * 64 + l];
    u64 s6 = selfw[(size_t)6 * 64 + l];
    u64 s7 = selfw[(size_t)7 * 64 + l];

    int cnt = 0;
    bool done = false;
    for (int w = 0; w < 157; ++w) {
        u64 swreg = s0;
        s0 = s1; s1 = s2; s2 = s3; s3 = s4; s4 = s5; s5 = s6; s6 = s7;
        s7 = (w + 8 < 157) ? selfw[(size_t)(w + 8) * 64 + l] : 0ull;

        int slot = w >> 6, owner = w & 63;
        u64 val = (slot == 0) ? r0 : (slot == 1) ? r1 : r2;
        u64 rw = rdlane64(val, owner);
        u64 wmask = (w == 156) ? 0xFFFFull : ~0ull;
        u64 av = (~rw) & wmask;

        // ---- intra-word greedy resolve: scalar chain via readlane ----
        u64 km = 0;
        while (av) {
            int b = __builtin_ctzll(av);
            u64 sw = rdlane64(swreg, b);
            km |= 1ull << b;
            av &= ~(1ull << b);
            av &= ~sw;
        }
        // ---- commit: OR kept rows in batches of 16 (loads back-to-back),
        //      skipping dead slots (slot0 dead for w>=63, slot1 for w>=127) ----
        bool need0 = (w < 63);
        bool need1 = (w < 127);
        u64 kk = km;
        while (kk) {
            int bsx[16];
            int nb = 0;
            while (kk && nb < 16) {
                int b = __builtin_ctzll(kk);
                kk &= kk - 1;
                bsx[nb++] = b;
            }
            u64 a0 = 0, a1 = 0, a2 = 0;
#pragma unroll
            for (int u = 0; u < 16; ++u) {
                if (u < nb) {
                    int i = (w << 6) + bsx[u];
                    if (l == 0 && cnt + u < 2000) keptList[cnt + u] = i;
                    const u64* rp = rows + (size_t)i * NWORDS;
                    if (need0) a0 |= rp[l];
                    if (need1) a1 |= rp[64 + l];
                    if (l < 32) a2 |= rp[128 + l];
                }
            }
            if (need0) r0 |= a0;
            if (need1) r1 |= a1;
            r2 |= a2;
            cnt += nb;
            if (cnt >= 2000) { done = true; break; }
        }
        if (done) break;
    }
    if (l == 0) kcnt = (cnt < 2000) ? cnt : 2000;
    __syncthreads();
    int K = kcnt;
    for (int r = l; r < 2000; r += 64) {
        if (r < K) {
            int j = keptList[r];
            out[r * 4 + 0] = sx1[j];
            out[r * 4 + 1] = sy1[j];
            out[r * 4 + 2] = sx2[j];
            out[r * 4 + 3] = sy2[j];
            out[8000 + r]  = sS[j];
        } else {
            out[r * 4 + 0] = 0.f; out[r * 4 + 1] = 0.f;
            out[r * 4 + 2] = 0.f; out[r * 4 + 3] = 0.f;
            out[8000 + r]  = 0.f;
        }
    }
}

// ---------------------------------------------------------------------------
extern "C" void kernel_launch(void* const* d_in, const int* in_sizes, int n_in,
                              void* d_out, int out_size, void* d_ws, size_t ws_size,
                              hipStream_t stream)
{
    (void)in_sizes; (void)n_in; (void)out_size;
    const float* feat = (const float*)d_in[1];
    const float* wrpn = (const float*)d_in[3];
    const float* brpn = (const float*)d_in[4];
    const float* wcls = (const float*)d_in[5];
    const float* bcls = (const float*)d_in[6];
    const float* wreg = (const float*)d_in[7];
    const float* breg = (const float*)d_in[8];
    float* out = (float*)d_out;

    // K-split factor by workspace budget. need(ns) = ns*512*2560*4 + 16,252,928.
    int ns = (ws_size >= 58195968) ? 8 : (ws_size >= 37224448) ? 4 : 2;
    int cpt     = 8 / ns;                 // 64c-chunks per tap per z-slice
    int cptLog  = (ns == 2) ? 2 : (ns == 4) ? 1 : 0;
    int cptm1   = cpt - 1;
    int cptMul  = cpt * 64;               // c0base = bs * cptMul
    int niter   = 9 * cpt;
    size_t pkB = (size_t)ns * 512 * 2560 * 4;

    char* ws = (char*)d_ws;
    // Live ranges:
    //   [0,pkB)            pk     k1m..k2a
    //   [pkB,pkB+16.25M)   Xt+W   kprep..k1m; then smalls (k2a+), part
    //                      (k2a..k2b) and rows (memset/k4..k5) share offsets.
    float* pk = (float*)ws;
    unsigned short* Xthi = (unsigned short*)(ws + pkB);
    unsigned short* Xtlo = Xthi + (size_t)52 * 64 * 512;
    unsigned short* Whi  = (unsigned short*)(ws + pkB + 6815744);
    unsigned short* Wlo  = Whi + (size_t)512 * 4608;

    char* sm = ws + pkB;
    float* score = (float*)(sm + 0);             // 90,000
    float* bx1   = (float*)(sm + 90000);
    float* by1   = (float*)(sm + 180000);
    float* bx2   = (float*)(sm + 270000);
    float* by2   = (float*)(sm + 360000);
    u32*   valid = (u32*)  (sm + 450000);        // 90,000
    u64*   key   = (u64*)  (sm + 540000);        // 180,000
    u32*   rankp = (u32*)  (sm + 720000);        // 900,000 (10 chunks)
    float* sS    = (float*)(sm + 1620000);       // 40,000
    float* sx1   = (float*)(sm + 1660000);
    float* sy1   = (float*)(sm + 1700000);
    float* sx2   = (float*)(sm + 1740000);
    float* sy2   = (float*)(sm + 1780000);
    u32*   sInv  = (u32*)  (sm + 1820000);       // 40,960
    u64*   selfw = (u64*)  (sm + 1860960);       // 81,920
    float4* sbox4= (float4*)(sm + 1942880);      // 163,840 (10240 entries)
    float* part  = (float*)(sm + 2106720);       // 3,600,000 (k2a..k2b)
    u64*   rows  = (u64*)  (sm + 2106720);       // 12,800,000 (k4..k5) -> ends sm+14.91M < 16.25M
    // peak footprint = pkB + 16,252,928 (ns=4 -> 37.2 MB, proven available)

    AnchorBase ab;
    {
        const float scales[3] = {128.f, 256.f, 512.f};
        const float aspect[3] = {0.5f, 1.f, 2.f};
        for (int ai = 0; ai < 3; ++ai) {
            float hr = sqrtf(aspect[ai]);
            float wratio = 1.0f / hr;
            for (int si = 0; si < 3; ++si) {
                float wsz = wratio * scales[si];
                float hsz = hr * scales[si];
                int a = ai * 3 + si;
                ab.b[a * 4 + 0] = rintf(-wsz / 2.0f);
                ab.b[a * 4 + 1] = rintf(-hsz / 2.0f);
                ab.b[a * 4 + 2] = rintf( wsz / 2.0f);
                ab.b[a * 4 + 3] = rintf( hsz / 2.0f);
            }
        }
    }

    kprep    <<<928, 256, 0, stream>>>(feat, wrpn, Xthi, Xtlo, Whi, Wlo);
    k1m      <<<dim3(4, 40, ns), 256, 0, stream>>>(Xthi, Xtlo, Whi, Wlo, pk,
                                                   cptLog, cptm1, cptMul, niter);
    k2a_heads<<<dim3(40, 8), 256, 0, stream>>>(pk, ns, brpn, wcls, wreg, part);
    k2b_decode<<<88, 256, 0, stream>>>(part, bcls, breg, ab, score, bx1, by1, bx2, by2, valid, key);
    k3a_rank <<<dim3(22, 10), 256, 0, stream>>>(key, rankp);
    k3b_gather<<<88, 256, 0, stream>>>(rankp, score, bx1, by1, bx2, by2, valid,
                                       sS, sx1, sy1, sx2, sy2, sbox4, sInv);
    hipMemsetAsync(rows, 0, (size_t)PRE_TOPK * NWORDS * 8, stream);   // sub-diagonal + tail words
    k4_mat   <<<2500, 256, 0, stream>>>(sbox4, rows, selfw);
    k5_scan  <<<1, 64, 0, stream>>>(rows, selfw, sInv, sS, sx1, sy1, sx2, sy2, out);
}